// Round 9
// baseline (3306.426 us; speedup 1.0000x reference)
//
#include <hip/hip_runtime.h>
#include <hip/hip_bf16.h>

#define NSTEPS 64

typedef __attribute__((ext_vector_type(8))) short bf16x8;
typedef __attribute__((ext_vector_type(4))) float f32x4;

static __device__ __forceinline__ unsigned int cvtpk_bf16(float lo, float hi) {
  unsigned int d;
  asm("v_cvt_pk_bf16_f32 %0, %1, %2" : "=v"(d) : "v"(lo), "v"(hi));
  return d;
}

// ---------------------------------------------------------------------------
// prep (UNCHANGED, verified rounds 1/2/4/5/6/7): MFMA A-fragments for W1/W2.
// A1 frags: [mb=8][kc=5][lane=64][j=8] bf16, PERMUTED co:
//   co(mb, m) = (mb>>1)*32 + (m>>2)*8 + (mb&1)*4 + (m&3),  m = lane&15,
//   k = 32*kc + 8*(lane>>4) + j,  k = tap*16 + ci, zero for k>=144.
// GEMM1 acc of mb pair {2q,2q+1} IS the lane-exact GEMM2 B-fragment kc2=mb>>1.
// W2 frags at element 20480: [kc2=4][lane=64][j=8], natural k2 order.
// ---------------------------------------------------------------------------
__global__ void ca_prep(const float* __restrict__ w1, const float* __restrict__ w2,
                        __hip_bfloat16* __restrict__ fr) {
  int i = blockIdx.x * 256 + threadIdx.x;
  if (i < 20480) {
    int j  = i & 7;
    int l  = (i >> 3) & 63;
    int fi = i >> 9;          // mb*5 + kc
    int kc = fi % 5, mb = fi / 5;
    int m  = l & 15;
    int co = ((mb >> 1) << 5) + ((m >> 2) << 3) + ((mb & 1) << 2) + (m & 3);
    int k  = kc * 32 + ((l >> 4) << 3) + j;
    float v = 0.0f;
    if (k < 144) {
      int tap = k >> 4, ci = k & 15;
      v = w1[(co * 16 + ci) * 9 + tap];   // w1[co][ci][dy][dx], tap=dy*3+dx
    }
    fr[i] = __float2bfloat16(v);
  } else if (i < 22528) {
    int i2  = i - 20480;
    int j   = i2 & 7;
    int l   = (i2 >> 3) & 63;
    int kc2 = i2 >> 9;
    int k2  = kc2 * 32 + ((l >> 4) << 3) + j;
    fr[i] = __float2bfloat16(w2[(l & 15) * 128 + k2]);
  }
}

// ---------------------------------------------------------------------------
// one CA step.  ROUND-6 STRUCTURE VERBATIM (verified passing), with the only
// change being staging single-buffered (+ trailing barrier, the round-7-
// verified sync pattern) to shrink LDS 26752 -> 18560 B so the 2048-block
// grid is EXACTLY 8 blocks/CU resident (full residency, zero tail).
//
// State mid-run: NHWC f32, elem = (b<<20)+(y<<12)+(x<<4)+c.
// Step 0 reads NCHW x; step 63 writes NCHW d_out.
//
// grid = 2048: b = bid&7 (batch->XCD), 16x16 grid of 16x16-px tiles.
// block = 128 threads = 2 waves.  Wave w owns co slice mb {4w..4w+3}.
// j loop (8 iters, row pair {2j, 2j+1}):
//   phase A: GEMM1 both rows on this wave's co slice (kc-outer, A1 frag
//            fetched once per j from global/L2), stage relu(p) as ready-made
//            GEMM2 B-fragments into slot[i=row][kc2=2w+q] (verified packing)
//   barrier
//   phase B: wave w does GEMM2 + epilogue for row 2j+w
//   barrier (slots reused next j — single-buffered)
//
// LDS (18560 B, 8 blocks/CU):
//   [    0,  8192)  relu(p) staging [i=2][kc2=4][lane=64]x16B
//   [ 8192, 13376)  h tile ci 0..7,  [y=18][x=18] x 16B/pixel
//   [13376, 18560)  h tile ci 8..15, same
// ---------------------------------------------------------------------------
#define TILE0 8192
#define TILE1 13376

template <bool IN_NCHW, bool OUT_NCHW>
__launch_bounds__(128, 4)
__global__ void ca_step(const float* __restrict__ hin,
                        float* __restrict__ hout,
                        const __hip_bfloat16* __restrict__ fr) {
  __shared__ __align__(16) char smem[18560];
  const int tid  = threadIdx.x;
  const int lane = tid & 63;
  const int w    = tid >> 6;          // 0..1
  const int bid  = blockIdx.x;
  const int b    = bid & 7;           // batch -> XCD round-robin
  const int t    = bid >> 3;          // 0..255
  const int ty   = t >> 4;            // 0..15
  const int tx   = t & 15;            // 0..15
  const int Y0   = ty << 4, X0 = tx << 4;
  const int ib   = b << 20;           // per-batch elems: 2^20 in BOTH layouts

  // ---- W2 resident (16 VGPR) ----
  bf16x8 w2f[4];
#pragma unroll
  for (int kc = 0; kc < 4; ++kc)
    w2f[kc] = *(const bf16x8*)(fr + 20480 + ((kc * 64 + lane) << 3));
#pragma unroll
  for (int kc = 0; kc < 4; ++kc)
    asm volatile("" : "+v"(w2f[kc]));

  // ---- halo'd tile load: 18x18 px x 16 ch, f32 -> bf16 via cvt_pk ----
  for (int i = tid; i < 18 * 18; i += 128) {
    int y  = i / 18;
    int x  = i - y * 18;
    int GY = Y0 + y - 1, GX = X0 + x - 1;
    bool inb = ((unsigned)GY < 256u) && ((unsigned)GX < 256u);
    unsigned int pk[8];
    if (IN_NCHW) {
      int gof = ib + (GY << 8) + GX;
#pragma unroll
      for (int c = 0; c < 8; ++c) {
        float v0 = inb ? hin[gof + ((2 * c) << 16)] : 0.0f;
        float v1 = inb ? hin[gof + ((2 * c + 1) << 16)] : 0.0f;
        pk[c] = cvtpk_bf16(v0, v1);
      }
    } else {
      // NHWC: one 64 B record, 4x dwordx4, fully coalesced
      f32x4 q[4];
      if (inb) {
        const f32x4* rp = (const f32x4*)(hin + ib + (GY << 12) + (GX << 4));
#pragma unroll
        for (int qq = 0; qq < 4; ++qq) q[qq] = rp[qq];
      } else {
        const f32x4 z = {0.0f, 0.0f, 0.0f, 0.0f};
#pragma unroll
        for (int qq = 0; qq < 4; ++qq) q[qq] = z;
      }
#pragma unroll
      for (int c = 0; c < 8; ++c)
        pk[c] = cvtpk_bf16(q[c >> 1][(c & 1) * 2], q[c >> 1][(c & 1) * 2 + 1]);
    }
    *(uint4*)(smem + TILE0 + i * 16) = make_uint4(pk[0], pk[1], pk[2], pk[3]);
    *(uint4*)(smem + TILE1 + i * 16) = make_uint4(pk[4], pk[5], pk[6], pk[7]);
  }
  __syncthreads();

  const int pix     = lane & 15;
  const int g       = lane >> 4;
  const int g1b     = g >> 1;                        // tap-select bit
  const int halfoff = (g & 1) ? TILE1 : TILE0;       // ci half

  const f32x4 z4 = {0.0f, 0.0f, 0.0f, 0.0f};

#pragma unroll 1
  for (int j = 0; j < 8; ++j) {
    // hv prefetch: this wave's phase-B pixel-block (row 2j+w), issue early
    const int py = Y0 + 2 * j + w;
    float hv[4];
    if (IN_NCHW) {
      const int gbB = ib + (py << 8) + X0 + pix;
#pragma unroll
      for (int r = 0; r < 4; ++r)
        hv[r] = hin[gbB + (((g << 2) + r) << 16)];
    } else {
      const f32x4 hvv =
          *(const f32x4*)(hin + ib + (py << 12) + ((X0 + pix) << 4) + (g << 2));
#pragma unroll
      for (int r = 0; r < 4; ++r) hv[r] = hvv[r];
    }

    // ---- phase A: GEMM1 rows 2j+0, 2j+1, kc-outer (frag fetched once/j) ----
    f32x4 acc[2][4];
#pragma unroll
    for (int i = 0; i < 2; ++i)
#pragma unroll
      for (int ml = 0; ml < 4; ++ml) acc[i][ml] = z4;

#pragma unroll
    for (int kc = 0; kc < 5; ++kc) {
      bf16x8 a1c[4];
#pragma unroll
      for (int ml = 0; ml < 4; ++ml) {
        const int mb = (w << 2) + ml;
        a1c[ml] = *(const bf16x8*)(fr + (((mb * 5 + kc) * 64 + lane) << 3));
      }
      const int t0   = 2 * kc;
      const int t1   = (2 * kc + 1 > 8) ? 8 : 2 * kc + 1;  // tap 9 zero-pad
      const int off0 = ((t0 / 3) * 18 + (t0 % 3)) * 16;    // compile-time
      const int off1 = ((t1 / 3) * 18 + (t1 % 3)) * 16;
#pragma unroll
      for (int i = 0; i < 2; ++i) {
        const char* rowbase = smem + halfoff + ((2 * j + i) * 18 + pix) * 16;
        const bf16x8 b1 = *(const bf16x8*)(rowbase + (g1b ? off1 : off0));
#pragma unroll
        for (int ml = 0; ml < 4; ++ml)
          acc[i][ml] = __builtin_amdgcn_mfma_f32_16x16x32_bf16(a1c[ml], b1,
                                                               acc[i][ml], 0, 0, 0);
      }
    }

    // stage relu(p) as B-fragments: slot[i][kc2 = 2w+q]  (verified packing)
#pragma unroll
    for (int i = 0; i < 2; ++i) {
#pragma unroll
      for (int q = 0; q < 2; ++q) {
        const int me = 2 * q, mo = 2 * q + 1;
        union { unsigned int u[4]; bf16x8 v; } bb;
        bb.u[0] = cvtpk_bf16(fmaxf(acc[i][me][0], 0.0f), fmaxf(acc[i][me][1], 0.0f));
        bb.u[1] = cvtpk_bf16(fmaxf(acc[i][me][2], 0.0f), fmaxf(acc[i][me][3], 0.0f));
        bb.u[2] = cvtpk_bf16(fmaxf(acc[i][mo][0], 0.0f), fmaxf(acc[i][mo][1], 0.0f));
        bb.u[3] = cvtpk_bf16(fmaxf(acc[i][mo][2], 0.0f), fmaxf(acc[i][mo][3], 0.0f));
        *(bf16x8*)(smem + (i << 12) + (((w << 1) + q) << 10) + (lane << 4)) = bb.v;
      }
    }
    __syncthreads();

    // ---- phase B: GEMM2 + epilogue for row 2j+w ----
    f32x4 dxa = z4;
    const char* bs = smem + (w << 12) + (lane << 4);
#pragma unroll
    for (int kc2 = 0; kc2 < 4; ++kc2) {
      const bf16x8 b2 = *(const bf16x8*)(bs + (kc2 << 10));
      dxa = __builtin_amdgcn_mfma_f32_16x16x32_bf16(w2f[kc2], b2, dxa, 0, 0, 0);
    }

    if (OUT_NCHW) {
      const int gbo = ib + (py << 8) + X0 + pix;
#pragma unroll
      for (int r = 0; r < 4; ++r) {
        const int co2 = (g << 2) + r;
        float v = hv[r] + dxa[r];
        const float lo = (co2 == 0) ? 0.0f : -3.0f;
        const float hi = (co2 == 0) ? 1.0f : 3.0f;
        v = fminf(fmaxf(v, lo), hi);
        hout[gbo + (co2 << 16)] = v;
      }
    } else {
      f32x4 ov;
#pragma unroll
      for (int r = 0; r < 4; ++r) {
        const int co2 = (g << 2) + r;
        float v = hv[r] + dxa[r];
        const float lo = (co2 == 0) ? 0.0f : -3.0f;
        const float hi = (co2 == 0) ? 1.0f : 3.0f;
        ov[r] = fminf(fmaxf(v, lo), hi);
      }
      *(f32x4*)(hout + ib + (py << 12) + ((X0 + pix) << 4) + (g << 2)) = ov;
    }
    __syncthreads();   // single-buffered staging: slots reused by next j
  }
}

// ---------------------------------------------------------------------------
extern "C" void kernel_launch(void* const* d_in, const int* in_sizes, int n_in,
                              void* d_out, int out_size, void* d_ws, size_t ws_size,
                              hipStream_t stream) {
  const float* x  = (const float*)d_in[0];
  const float* w1 = (const float*)d_in[1];
  const float* w2 = (const float*)d_in[2];
  float* out  = (float*)d_out;                  // NHWC scratch mid-run; NCHW at s=63
  float* ping = (float*)d_ws;                   // 33.5 MB NHWC state
  __hip_bfloat16* fr = (__hip_bfloat16*)((char*)d_ws + 33554432);

  ca_prep<<<88, 256, 0, stream>>>(w1, w2, fr);

  for (int s = 0; s < NSTEPS; ++s) {
    const float* in = (s == 0) ? x : ((s & 1) ? ping : out);
    float* o        = (s & 1) ? out : ping;     // s=63 (odd) -> d_out
    if (s == 0)
      ca_step<true, false><<<2048, 128, 0, stream>>>(in, o, fr);
    else if (s == NSTEPS - 1)
      ca_step<false, true><<<2048, 128, 0, stream>>>(in, o, fr);
    else
      ca_step<false, false><<<2048, 128, 0, stream>>>(in, o, fr);
  }
}

// Round 10
// 1711.325 us; speedup vs baseline: 1.9321x; 1.9321x over previous
//
#include <hip/hip_runtime.h>
#include <hip/hip_bf16.h>

#define NSTEPS 64

typedef __attribute__((ext_vector_type(8))) short bf16x8;
typedef __attribute__((ext_vector_type(4))) float f32x4;

static __device__ __forceinline__ unsigned int cvtpk_bf16(float lo, float hi) {
  unsigned int d;
  asm("v_cvt_pk_bf16_f32 %0, %1, %2" : "=v"(d) : "v"(lo), "v"(hi));
  return d;
}

// ---------------------------------------------------------------------------
// prep (UNCHANGED, verified rounds 1/2/4/5/6/7/9): MFMA A-fragments W1/W2.
// A1 frags: [mb=8][kc=5][lane=64][j=8] bf16, PERMUTED co:
//   co(mb, m) = (mb>>1)*32 + (m>>2)*8 + (mb&1)*4 + (m&3),  m = lane&15,
//   k = 32*kc + 8*(lane>>4) + j,  k = tap*16 + ci, zero for k>=144.
// GEMM1 acc of mb pair {2q,2q+1} IS the lane-exact GEMM2 B-fragment kc2=q.
// W2 frags at element 20480: [kc2=4][lane=64][j=8], natural k2 order.
// ---------------------------------------------------------------------------
__global__ void ca_prep(const float* __restrict__ w1, const float* __restrict__ w2,
                        __hip_bfloat16* __restrict__ fr) {
  int i = blockIdx.x * 256 + threadIdx.x;
  if (i < 20480) {
    int j  = i & 7;
    int l  = (i >> 3) & 63;
    int fi = i >> 9;          // mb*5 + kc
    int kc = fi % 5, mb = fi / 5;
    int m  = l & 15;
    int co = ((mb >> 1) << 5) + ((m >> 2) << 3) + ((mb & 1) << 2) + (m & 3);
    int k  = kc * 32 + ((l >> 4) << 3) + j;
    float v = 0.0f;
    if (k < 144) {
      int tap = k >> 4, ci = k & 15;
      v = w1[(co * 16 + ci) * 9 + tap];   // w1[co][ci][dy][dx], tap=dy*3+dx
    }
    fr[i] = __float2bfloat16(v);
  } else if (i < 22528) {
    int i2  = i - 20480;
    int j   = i2 & 7;
    int l   = (i2 >> 3) & 63;
    int kc2 = i2 >> 9;
    int k2  = kc2 * 32 + ((l >> 4) << 3) + j;
    fr[i] = __float2bfloat16(w2[(l & 15) * 128 + k2]);
  }
}

// ---------------------------------------------------------------------------
// one CA step.  State mid-run: NHWC f32, elem = (b<<20)+(y<<12)+(x<<4)+c.
// Step 0 reads NCHW x; step 63 writes NCHW d_out.
//
// 4-WAVE RESHAPE of the round-7-verified 4-row phase structure:
// grid = 2048: b = bid&7 (batch->XCD), 16x16 grid of 16x16-px tiles.
// block = 256 threads = 4 waves.  Wave w owns co slice mb {2w, 2w+1}
// (= exactly GEMM2 chunk kc2 = w).  Per-wave regs: acc[4][2]=32 + a1c[2]=8
// (HALF of round 7's spilling footprint; round 9 proved spills = regression).
// j loop (4 iters, rows 4j..4j+3):
//   phase A: GEMM1 all 4 rows on this wave's 2 mb (kc-outer, 10 frag
//            fetches/j from L2 — half of round 6's traffic), stage relu(p)
//            as ready-made GEMM2 B-fragments: slot[row i][kc2=w] (verified
//            packing, me=ml0, mo=ml1)
//   barrier
//   phase B: wave w does GEMM2 + epilogue for row 4j+w (4 MFMA)
//   barrier (slots reused next j — single-buffered, round-9-verified)
//
// LDS (26752 B, ~6 blocks/CU = ~24 waves/CU, 2x round 6):
//   [    0, 16384)  relu(p) staging [i=4][kc2=4][lane=64]x16B
//   [16384, 21568)  h tile ci 0..7,  [y=18][x=18] x 16B/pixel
//   [21568, 26752)  h tile ci 8..15, same
// ---------------------------------------------------------------------------
#define TILE0 16384
#define TILE1 21568

template <bool IN_NCHW, bool OUT_NCHW>
__launch_bounds__(256, 2)
__global__ void ca_step(const float* __restrict__ hin,
                        float* __restrict__ hout,
                        const __hip_bfloat16* __restrict__ fr) {
  __shared__ __align__(16) char smem[26752];
  const int tid  = threadIdx.x;
  const int lane = tid & 63;
  const int w    = tid >> 6;          // 0..3
  const int bid  = blockIdx.x;
  const int b    = bid & 7;           // batch -> XCD round-robin
  const int t    = bid >> 3;          // 0..255
  const int ty   = t >> 4;            // 0..15
  const int tx   = t & 15;            // 0..15
  const int Y0   = ty << 4, X0 = tx << 4;
  const int ib   = b << 20;           // per-batch elems: 2^20 in BOTH layouts

  // ---- W2 resident (16 VGPR) ----
  bf16x8 w2f[4];
#pragma unroll
  for (int kc = 0; kc < 4; ++kc)
    w2f[kc] = *(const bf16x8*)(fr + 20480 + ((kc * 64 + lane) << 3));
#pragma unroll
  for (int kc = 0; kc < 4; ++kc)
    asm volatile("" : "+v"(w2f[kc]));

  // ---- halo'd tile load: 18x18 px x 16 ch, f32 -> bf16 via cvt_pk ----
  for (int i = tid; i < 18 * 18; i += 256) {
    int y  = i / 18;
    int x  = i - y * 18;
    int GY = Y0 + y - 1, GX = X0 + x - 1;
    bool inb = ((unsigned)GY < 256u) && ((unsigned)GX < 256u);
    unsigned int pk[8];
    if (IN_NCHW) {
      int gof = ib + (GY << 8) + GX;
#pragma unroll
      for (int c = 0; c < 8; ++c) {
        float v0 = inb ? hin[gof + ((2 * c) << 16)] : 0.0f;
        float v1 = inb ? hin[gof + ((2 * c + 1) << 16)] : 0.0f;
        pk[c] = cvtpk_bf16(v0, v1);
      }
    } else {
      // NHWC: one 64 B record, 4x dwordx4, fully coalesced
      f32x4 q[4];
      if (inb) {
        const f32x4* rp = (const f32x4*)(hin + ib + (GY << 12) + (GX << 4));
#pragma unroll
        for (int qq = 0; qq < 4; ++qq) q[qq] = rp[qq];
      } else {
        const f32x4 z = {0.0f, 0.0f, 0.0f, 0.0f};
#pragma unroll
        for (int qq = 0; qq < 4; ++qq) q[qq] = z;
      }
#pragma unroll
      for (int c = 0; c < 8; ++c)
        pk[c] = cvtpk_bf16(q[c >> 1][(c & 1) * 2], q[c >> 1][(c & 1) * 2 + 1]);
    }
    *(uint4*)(smem + TILE0 + i * 16) = make_uint4(pk[0], pk[1], pk[2], pk[3]);
    *(uint4*)(smem + TILE1 + i * 16) = make_uint4(pk[4], pk[5], pk[6], pk[7]);
  }
  __syncthreads();

  const int pix     = lane & 15;
  const int g       = lane >> 4;
  const int g1b     = g >> 1;                        // tap-select bit
  const int halfoff = (g & 1) ? TILE1 : TILE0;       // ci half

  const f32x4 z4 = {0.0f, 0.0f, 0.0f, 0.0f};

#pragma unroll 1
  for (int j = 0; j < 4; ++j) {
    // hv prefetch: this wave's phase-B row (4j+w), issue early
    const int py = Y0 + 4 * j + w;
    float hv[4];
    if (IN_NCHW) {
      const int gbB = ib + (py << 8) + X0 + pix;
#pragma unroll
      for (int r = 0; r < 4; ++r)
        hv[r] = hin[gbB + (((g << 2) + r) << 16)];
    } else {
      const f32x4 hvv =
          *(const f32x4*)(hin + ib + (py << 12) + ((X0 + pix) << 4) + (g << 2));
#pragma unroll
      for (int r = 0; r < 4; ++r) hv[r] = hvv[r];
    }

    // ---- phase A: GEMM1 rows 4j..4j+3 on mb {2w, 2w+1}, kc-outer ----
    f32x4 acc[4][2];
#pragma unroll
    for (int i = 0; i < 4; ++i)
#pragma unroll
      for (int ml = 0; ml < 2; ++ml) acc[i][ml] = z4;

#pragma unroll
    for (int kc = 0; kc < 5; ++kc) {
      bf16x8 a1c[2];
#pragma unroll
      for (int ml = 0; ml < 2; ++ml) {
        const int mb = (w << 1) + ml;
        a1c[ml] = *(const bf16x8*)(fr + (((mb * 5 + kc) * 64 + lane) << 3));
      }
      const int t0   = 2 * kc;
      const int t1   = (2 * kc + 1 > 8) ? 8 : 2 * kc + 1;  // tap 9 zero-pad
      const int off0 = ((t0 / 3) * 18 + (t0 % 3)) * 16;    // compile-time
      const int off1 = ((t1 / 3) * 18 + (t1 % 3)) * 16;
#pragma unroll
      for (int i = 0; i < 4; ++i) {
        const char* rowbase = smem + halfoff + ((4 * j + i) * 18 + pix) * 16;
        const bf16x8 b1 = *(const bf16x8*)(rowbase + (g1b ? off1 : off0));
#pragma unroll
        for (int ml = 0; ml < 2; ++ml)
          acc[i][ml] = __builtin_amdgcn_mfma_f32_16x16x32_bf16(a1c[ml], b1,
                                                               acc[i][ml], 0, 0, 0);
      }
    }

    // stage relu(p): slot[i][kc2=w] — verified packing (me=ml0, mo=ml1)
#pragma unroll
    for (int i = 0; i < 4; ++i) {
      union { unsigned int u[4]; bf16x8 v; } bb;
      bb.u[0] = cvtpk_bf16(fmaxf(acc[i][0][0], 0.0f), fmaxf(acc[i][0][1], 0.0f));
      bb.u[1] = cvtpk_bf16(fmaxf(acc[i][0][2], 0.0f), fmaxf(acc[i][0][3], 0.0f));
      bb.u[2] = cvtpk_bf16(fmaxf(acc[i][1][0], 0.0f), fmaxf(acc[i][1][1], 0.0f));
      bb.u[3] = cvtpk_bf16(fmaxf(acc[i][1][2], 0.0f), fmaxf(acc[i][1][3], 0.0f));
      *(bf16x8*)(smem + (i << 12) + (w << 10) + (lane << 4)) = bb.v;
    }
    __syncthreads();

    // ---- phase B: GEMM2 + epilogue for row 4j+w ----
    f32x4 dxa = z4;
    const char* bs = smem + (w << 12) + (lane << 4);
#pragma unroll
    for (int kc2 = 0; kc2 < 4; ++kc2) {
      const bf16x8 b2 = *(const bf16x8*)(bs + (kc2 << 10));
      dxa = __builtin_amdgcn_mfma_f32_16x16x32_bf16(w2f[kc2], b2, dxa, 0, 0, 0);
    }

    if (OUT_NCHW) {
      const int gbo = ib + (py << 8) + X0 + pix;
#pragma unroll
      for (int r = 0; r < 4; ++r) {
        const int co2 = (g << 2) + r;
        float v = hv[r] + dxa[r];
        const float lo = (co2 == 0) ? 0.0f : -3.0f;
        const float hi = (co2 == 0) ? 1.0f : 3.0f;
        v = fminf(fmaxf(v, lo), hi);
        hout[gbo + (co2 << 16)] = v;
      }
    } else {
      f32x4 ov;
#pragma unroll
      for (int r = 0; r < 4; ++r) {
        const int co2 = (g << 2) + r;
        float v = hv[r] + dxa[r];
        const float lo = (co2 == 0) ? 0.0f : -3.0f;
        const float hi = (co2 == 0) ? 1.0f : 3.0f;
        ov[r] = fminf(fmaxf(v, lo), hi);
      }
      *(f32x4*)(hout + ib + (py << 12) + ((X0 + pix) << 4) + (g << 2)) = ov;
    }
    __syncthreads();   // single-buffered staging: slots reused by next j
  }
}

// ---------------------------------------------------------------------------
extern "C" void kernel_launch(void* const* d_in, const int* in_sizes, int n_in,
                              void* d_out, int out_size, void* d_ws, size_t ws_size,
                              hipStream_t stream) {
  const float* x  = (const float*)d_in[0];
  const float* w1 = (const float*)d_in[1];
  const float* w2 = (const float*)d_in[2];
  float* out  = (float*)d_out;                  // NHWC scratch mid-run; NCHW at s=63
  float* ping = (float*)d_ws;                   // 33.5 MB NHWC state
  __hip_bfloat16* fr = (__hip_bfloat16*)((char*)d_ws + 33554432);

  ca_prep<<<88, 256, 0, stream>>>(w1, w2, fr);

  for (int s = 0; s < NSTEPS; ++s) {
    const float* in = (s == 0) ? x : ((s & 1) ? ping : out);
    float* o        = (s & 1) ? out : ping;     // s=63 (odd) -> d_out
    if (s == 0)
      ca_step<true, false><<<2048, 256, 0, stream>>>(in, o, fr);
    else if (s == NSTEPS - 1)
      ca_step<false, true><<<2048, 256, 0, stream>>>(in, o, fr);
    else
      ca_step<false, false><<<2048, 256, 0, stream>>>(in, o, fr);
  }
}

// Round 11
// 1702.329 us; speedup vs baseline: 1.9423x; 1.0053x over previous
//
#include <hip/hip_runtime.h>
#include <hip/hip_bf16.h>

#define NSTEPS 64

typedef __attribute__((ext_vector_type(8))) short bf16x8;
typedef __attribute__((ext_vector_type(4))) float f32x4;

static __device__ __forceinline__ unsigned int cvtpk_bf16(float lo, float hi) {
  unsigned int d;
  asm("v_cvt_pk_bf16_f32 %0, %1, %2" : "=v"(d) : "v"(lo), "v"(hi));
  return d;
}

// Opaque 16B global load: the compiler cannot rematerialize an asm-produced
// value, so these weight fragments STAY in registers across the j loop
// (invariant-load remat defeated rounds 2/5/10's residency attempts).
static __device__ __forceinline__ bf16x8 gload16(const __hip_bfloat16* p) {
  bf16x8 r;
  asm volatile("global_load_dwordx4 %0, %1, off" : "=v"(r) : "v"(p));
  return r;
}

// ---------------------------------------------------------------------------
// prep (UNCHANGED, verified rounds 1/2/4/5/6/7/9/10): MFMA A-fragments W1/W2.
// A1 frags: [mb=8][kc=5][lane=64][j=8] bf16, PERMUTED co:
//   co(mb, m) = (mb>>1)*32 + (m>>2)*8 + (mb&1)*4 + (m&3),  m = lane&15,
//   k = 32*kc + 8*(lane>>4) + j,  k = tap*16 + ci, zero for k>=144.
// GEMM1 acc of mb pair {2q,2q+1} IS the lane-exact GEMM2 B-fragment kc2=q.
// W2 frags at element 20480: [kc2=4][lane=64][j=8], natural k2 order.
// ---------------------------------------------------------------------------
__global__ void ca_prep(const float* __restrict__ w1, const float* __restrict__ w2,
                        __hip_bfloat16* __restrict__ fr) {
  int i = blockIdx.x * 256 + threadIdx.x;
  if (i < 20480) {
    int j  = i & 7;
    int l  = (i >> 3) & 63;
    int fi = i >> 9;          // mb*5 + kc
    int kc = fi % 5, mb = fi / 5;
    int m  = l & 15;
    int co = ((mb >> 1) << 5) + ((m >> 2) << 3) + ((mb & 1) << 2) + (m & 3);
    int k  = kc * 32 + ((l >> 4) << 3) + j;
    float v = 0.0f;
    if (k < 144) {
      int tap = k >> 4, ci = k & 15;
      v = w1[(co * 16 + ci) * 9 + tap];   // w1[co][ci][dy][dx], tap=dy*3+dx
    }
    fr[i] = __float2bfloat16(v);
  } else if (i < 22528) {
    int i2  = i - 20480;
    int j   = i2 & 7;
    int l   = (i2 >> 3) & 63;
    int kc2 = i2 >> 9;
    int k2  = kc2 * 32 + ((l >> 4) << 3) + j;
    fr[i] = __float2bfloat16(w2[(l & 15) * 128 + k2]);
  }
}

// ---------------------------------------------------------------------------
// one CA step.  ROUND-10 STRUCTURE VERBATIM (verified passing, 1711 us) with
// ONE change: all weight fragments loaded ONCE per step via opaque asm loads
// (resident ~56 VGPR), removing the per-j global refetch + latency chain.
//
// State mid-run: NHWC f32, elem = (b<<20)+(y<<12)+(x<<4)+c.
// Step 0 reads NCHW x; step 63 writes NCHW d_out.
//
// grid = 2048: b = bid&7 (batch->XCD), 16x16 grid of 16x16-px tiles.
// block = 256 threads = 4 waves.  Wave w owns co slice mb {2w, 2w+1}
// (= exactly GEMM2 chunk kc2 = w).
// j loop (4 iters, rows 4j..4j+3):
//   phase A: GEMM1 all 4 rows on this wave's 2 mb (weights in regs),
//            stage relu(p) into slot[row i][kc2=w] (verified packing)
//   barrier
//   phase B: wave w does GEMM2 + epilogue for row 4j+w
//   barrier (slots reused next j — single-buffered, verified)
//
// LDS (26752 B):
//   [    0, 16384)  relu(p) staging [i=4][kc2=4][lane=64]x16B
//   [16384, 21568)  h tile ci 0..7,  [y=18][x=18] x 16B/pixel
//   [21568, 26752)  h tile ci 8..15, same
// Residency: VGPR ~120 -> 4 waves/SIMD -> 4 blocks/CU -> grid = exactly
// 2 full residency waves, zero tail.
// ---------------------------------------------------------------------------
#define TILE0 16384
#define TILE1 21568

template <bool IN_NCHW, bool OUT_NCHW>
__launch_bounds__(256, 2)
__global__ void ca_step(const float* __restrict__ hin,
                        float* __restrict__ hout,
                        const __hip_bfloat16* __restrict__ fr) {
  __shared__ __align__(16) char smem[26752];
  const int tid  = threadIdx.x;
  const int lane = tid & 63;
  const int w    = tid >> 6;          // 0..3
  const int bid  = blockIdx.x;
  const int b    = bid & 7;           // batch -> XCD round-robin
  const int t    = bid >> 3;          // 0..255
  const int ty   = t >> 4;            // 0..15
  const int tx   = t & 15;            // 0..15
  const int Y0   = ty << 4, X0 = tx << 4;
  const int ib   = b << 20;           // per-batch elems: 2^20 in BOTH layouts

  // ---- resident weights via OPAQUE loads: wave w's A1 slice mb {2w,2w+1}
  //      (10 frags, 40 VGPR) + full W2 (4 frags, 16 VGPR) ----
  bf16x8 a1r[2][5];
#pragma unroll
  for (int ml = 0; ml < 2; ++ml)
#pragma unroll
    for (int kc = 0; kc < 5; ++kc) {
      const int mb = (w << 1) + ml;
      a1r[ml][kc] = gload16(fr + (((mb * 5 + kc) * 64 + lane) << 3));
    }
  bf16x8 w2f[4];
#pragma unroll
  for (int kc = 0; kc < 4; ++kc)
    w2f[kc] = gload16(fr + 20480 + ((kc * 64 + lane) << 3));
  asm volatile("s_waitcnt vmcnt(0)" ::: "memory");

  // ---- halo'd tile load: 18x18 px x 16 ch, f32 -> bf16 via cvt_pk ----
  for (int i = tid; i < 18 * 18; i += 256) {
    int y  = i / 18;
    int x  = i - y * 18;
    int GY = Y0 + y - 1, GX = X0 + x - 1;
    bool inb = ((unsigned)GY < 256u) && ((unsigned)GX < 256u);
    unsigned int pk[8];
    if (IN_NCHW) {
      int gof = ib + (GY << 8) + GX;
#pragma unroll
      for (int c = 0; c < 8; ++c) {
        float v0 = inb ? hin[gof + ((2 * c) << 16)] : 0.0f;
        float v1 = inb ? hin[gof + ((2 * c + 1) << 16)] : 0.0f;
        pk[c] = cvtpk_bf16(v0, v1);
      }
    } else {
      // NHWC: one 64 B record, 4x dwordx4, fully coalesced
      f32x4 q[4];
      if (inb) {
        const f32x4* rp = (const f32x4*)(hin + ib + (GY << 12) + (GX << 4));
#pragma unroll
        for (int qq = 0; qq < 4; ++qq) q[qq] = rp[qq];
      } else {
        const f32x4 z = {0.0f, 0.0f, 0.0f, 0.0f};
#pragma unroll
        for (int qq = 0; qq < 4; ++qq) q[qq] = z;
      }
#pragma unroll
      for (int c = 0; c < 8; ++c)
        pk[c] = cvtpk_bf16(q[c >> 1][(c & 1) * 2], q[c >> 1][(c & 1) * 2 + 1]);
    }
    *(uint4*)(smem + TILE0 + i * 16) = make_uint4(pk[0], pk[1], pk[2], pk[3]);
    *(uint4*)(smem + TILE1 + i * 16) = make_uint4(pk[4], pk[5], pk[6], pk[7]);
  }
  __syncthreads();

  const int pix     = lane & 15;
  const int g       = lane >> 4;
  const int g1b     = g >> 1;                        // tap-select bit
  const int halfoff = (g & 1) ? TILE1 : TILE0;       // ci half

  const f32x4 z4 = {0.0f, 0.0f, 0.0f, 0.0f};

#pragma unroll 1
  for (int j = 0; j < 4; ++j) {
    // hv prefetch: this wave's phase-B row (4j+w), issue early
    const int py = Y0 + 4 * j + w;
    float hv[4];
    if (IN_NCHW) {
      const int gbB = ib + (py << 8) + X0 + pix;
#pragma unroll
      for (int r = 0; r < 4; ++r)
        hv[r] = hin[gbB + (((g << 2) + r) << 16)];
    } else {
      const f32x4 hvv =
          *(const f32x4*)(hin + ib + (py << 12) + ((X0 + pix) << 4) + (g << 2));
#pragma unroll
      for (int r = 0; r < 4; ++r) hv[r] = hvv[r];
    }

    // ---- phase A: GEMM1 rows 4j..4j+3 on mb {2w, 2w+1}, weights in regs ----
    f32x4 acc[4][2];
#pragma unroll
    for (int i = 0; i < 4; ++i)
#pragma unroll
      for (int ml = 0; ml < 2; ++ml) acc[i][ml] = z4;

#pragma unroll
    for (int kc = 0; kc < 5; ++kc) {
      const int t0   = 2 * kc;
      const int t1   = (2 * kc + 1 > 8) ? 8 : 2 * kc + 1;  // tap 9 zero-pad
      const int off0 = ((t0 / 3) * 18 + (t0 % 3)) * 16;    // compile-time
      const int off1 = ((t1 / 3) * 18 + (t1 % 3)) * 16;
#pragma unroll
      for (int i = 0; i < 4; ++i) {
        const char* rowbase = smem + halfoff + ((4 * j + i) * 18 + pix) * 16;
        const bf16x8 b1 = *(const bf16x8*)(rowbase + (g1b ? off1 : off0));
#pragma unroll
        for (int ml = 0; ml < 2; ++ml)
          acc[i][ml] = __builtin_amdgcn_mfma_f32_16x16x32_bf16(a1r[ml][kc], b1,
                                                               acc[i][ml], 0, 0, 0);
      }
    }

    // stage relu(p): slot[i][kc2=w] — verified packing (me=ml0, mo=ml1)
#pragma unroll
    for (int i = 0; i < 4; ++i) {
      union { unsigned int u[4]; bf16x8 v; } bb;
      bb.u[0] = cvtpk_bf16(fmaxf(acc[i][0][0], 0.0f), fmaxf(acc[i][0][1], 0.0f));
      bb.u[1] = cvtpk_bf16(fmaxf(acc[i][0][2], 0.0f), fmaxf(acc[i][0][3], 0.0f));
      bb.u[2] = cvtpk_bf16(fmaxf(acc[i][1][0], 0.0f), fmaxf(acc[i][1][1], 0.0f));
      bb.u[3] = cvtpk_bf16(fmaxf(acc[i][1][2], 0.0f), fmaxf(acc[i][1][3], 0.0f));
      *(bf16x8*)(smem + (i << 12) + (w << 10) + (lane << 4)) = bb.v;
    }
    __syncthreads();

    // ---- phase B: GEMM2 + epilogue for row 4j+w ----
    f32x4 dxa = z4;
    const char* bs = smem + (w << 12) + (lane << 4);
#pragma unroll
    for (int kc2 = 0; kc2 < 4; ++kc2) {
      const bf16x8 b2 = *(const bf16x8*)(bs + (kc2 << 10));
      dxa = __builtin_amdgcn_mfma_f32_16x16x32_bf16(w2f[kc2], b2, dxa, 0, 0, 0);
    }

    if (OUT_NCHW) {
      const int gbo = ib + (py << 8) + X0 + pix;
#pragma unroll
      for (int r = 0; r < 4; ++r) {
        const int co2 = (g << 2) + r;
        float v = hv[r] + dxa[r];
        const float lo = (co2 == 0) ? 0.0f : -3.0f;
        const float hi = (co2 == 0) ? 1.0f : 3.0f;
        v = fminf(fmaxf(v, lo), hi);
        hout[gbo + (co2 << 16)] = v;
      }
    } else {
      f32x4 ov;
#pragma unroll
      for (int r = 0; r < 4; ++r) {
        const int co2 = (g << 2) + r;
        float v = hv[r] + dxa[r];
        const float lo = (co2 == 0) ? 0.0f : -3.0f;
        const float hi = (co2 == 0) ? 1.0f : 3.0f;
        ov[r] = fminf(fmaxf(v, lo), hi);
      }
      *(f32x4*)(hout + ib + (py << 12) + ((X0 + pix) << 4) + (g << 2)) = ov;
    }
    __syncthreads();   // single-buffered staging: slots reused by next j
  }
}

// ---------------------------------------------------------------------------
extern "C" void kernel_launch(void* const* d_in, const int* in_sizes, int n_in,
                              void* d_out, int out_size, void* d_ws, size_t ws_size,
                              hipStream_t stream) {
  const float* x  = (const float*)d_in[0];
  const float* w1 = (const float*)d_in[1];
  const float* w2 = (const float*)d_in[2];
  float* out  = (float*)d_out;                  // NHWC scratch mid-run; NCHW at s=63
  float* ping = (float*)d_ws;                   // 33.5 MB NHWC state
  __hip_bfloat16* fr = (__hip_bfloat16*)((char*)d_ws + 33554432);

  ca_prep<<<88, 256, 0, stream>>>(w1, w2, fr);

  for (int s = 0; s < NSTEPS; ++s) {
    const float* in = (s == 0) ? x : ((s & 1) ? ping : out);
    float* o        = (s & 1) ? out : ping;     // s=63 (odd) -> d_out
    if (s == 0)
      ca_step<true, false><<<2048, 256, 0, stream>>>(in, o, fr);
    else if (s == NSTEPS - 1)
      ca_step<false, true><<<2048, 256, 0, stream>>>(in, o, fr);
    else
      ca_step<false, false><<<2048, 256, 0, stream>>>(in, o, fr);
  }
}